// Round 1
// baseline (441.887 us; speedup 1.0000x reference)
//
#include <hip/hip_runtime.h>

#define Nn 4096
#define FIN 512
#define NH 8
#define O1 512

typedef __attribute__((ext_vector_type(8))) short short8;
typedef __attribute__((ext_vector_type(4))) float f32x4;
typedef __attribute__((ext_vector_type(4))) unsigned int u32x4;

__device__ __forceinline__ unsigned short f2bf(float f){
  union{float f; unsigned u;} x; x.f=f;
  unsigned r = x.u + 0x7fffu + ((x.u>>16)&1u);
  return (unsigned short)(r>>16);
}
__device__ __forceinline__ float bf2f(unsigned short b){
  union{unsigned u; float f;} x; x.u=((unsigned)b)<<16;
  return x.f;
}

// ---- pack adjacency int32 -> bitmask (one uint64 per 64 cols) ----
__global__ void k_pack_adj(const int* __restrict__ adj, unsigned long long* __restrict__ adjw){
  size_t tid = (size_t)blockIdx.x*blockDim.x + threadIdx.x;
  int v = adj[tid];
  unsigned long long m = __ballot(v>0);
  if((threadIdx.x&63)==0) adjw[tid>>6] = m;
}

// ---- f32 -> bf16 convert ----
__global__ void k_cvt(const float* __restrict__ in, unsigned short* __restrict__ out, int n){
  int i = (blockIdx.x*blockDim.x + threadIdx.x)*4;
  if(i>=n) return;
  float4 v = *(const float4*)(in+i);
  out[i+0]=f2bf(v.x); out[i+1]=f2bf(v.y); out[i+2]=f2bf(v.z); out[i+3]=f2bf(v.w);
}

// ---- C^T[o][m] = sum_k A[m][k]*B[o][k], bf16 in, bf16 out (transposed) ----
// block = 256 thr = 4 waves (2x2 of 32x32), tile 64x64, no LDS (frags direct from global)
__global__ void k_gemm_tn(const unsigned short* __restrict__ A, const unsigned short* __restrict__ B,
                          unsigned short* __restrict__ CT, int M, int K, int O){
  int t=threadIdx.x, l=t&63, w=t>>6;
  int wm=w&1, wo=w>>1;
  int m0=blockIdx.x*64, o0=blockIdx.y*64;
  int row=l&15, kq=(l>>4)*8;
  const unsigned short* Ab = A + (size_t)(m0+wm*32+row)*K + kq;
  const unsigned short* Bb = B + (size_t)(o0+wo*32+row)*K + kq;
  f32x4 acc[2][2]={};
  for(int k0=0;k0<K;k0+=32){
    short8 a0=*(const short8*)(Ab+k0);
    short8 a1=*(const short8*)(Ab+(size_t)16*K+k0);
    short8 b0=*(const short8*)(Bb+k0);
    short8 b1=*(const short8*)(Bb+(size_t)16*K+k0);
    acc[0][0]=__builtin_amdgcn_mfma_f32_16x16x32_bf16(a0,b0,acc[0][0],0,0,0);
    acc[0][1]=__builtin_amdgcn_mfma_f32_16x16x32_bf16(a0,b1,acc[0][1],0,0,0);
    acc[1][0]=__builtin_amdgcn_mfma_f32_16x16x32_bf16(a1,b0,acc[1][0],0,0,0);
    acc[1][1]=__builtin_amdgcn_mfma_f32_16x16x32_bf16(a1,b1,acc[1][1],0,0,0);
  }
  #pragma unroll
  for(int mi=0;mi<2;mi++)
  #pragma unroll
  for(int oi=0;oi<2;oi++)
  #pragma unroll
  for(int r=0;r<4;r++){
    int m = m0+wm*32+mi*16+(l>>4)*4+r;
    int o = o0+wo*32+oi*16+(l&15);
    CT[(size_t)o*M+m] = f2bf(acc[mi][oi][r]);
  }
}

// ---- wh1[h][n] = sum_c whT[h*64+c][n]*a1[h][c]; same for wh2 ----
__global__ void k_wh12(const unsigned short* __restrict__ whT,
                       const float* __restrict__ a1, const float* __restrict__ a2,
                       float* __restrict__ wh1, float* __restrict__ wh2){
  const int M=Nn;
  int n=blockIdx.x*blockDim.x+threadIdx.x;
  int h=blockIdx.y;
  float s1=0.f,s2=0.f;
  for(int c=0;c<64;c++){
    float v=bf2f(whT[(size_t)(h*64+c)*M+n]);
    s1+=v*a1[h*64+c];
    s2+=v*a2[h*64+c];
  }
  wh1[(size_t)h*M+n]=s1;
  wh2[(size_t)h*M+n]=s2;
}

// ---- per-row softmax max: m_i = LR(wh1_i + max_{j in N(i)} wh2_j) ----
// one wave per (row, head); lane l scans 64-bit word l
__global__ void k_rowmax(const unsigned long long* __restrict__ adjw,
                         const float* __restrict__ wh1, const float* __restrict__ wh2,
                         float* __restrict__ mrow){
  const int M=Nn;
  int w=threadIdx.x>>6, l=threadIdx.x&63;
  int i=blockIdx.x*4+w, h=blockIdx.y;
  unsigned long long word = adjw[(size_t)i*64 + l];
  const float* w2 = wh2 + (size_t)h*M + l*64;
  float mx=-3e38f;
  #pragma unroll
  for(int k=0;k<16;k++){
    float4 v=*(const float4*)(w2+k*4);
    unsigned b=(unsigned)(word>>(k*4))&0xfu;
    if(b&1u) mx=fmaxf(mx,v.x);
    if(b&2u) mx=fmaxf(mx,v.y);
    if(b&4u) mx=fmaxf(mx,v.z);
    if(b&8u) mx=fmaxf(mx,v.w);
  }
  #pragma unroll
  for(int s=32;s;s>>=1) mx=fmaxf(mx,__shfl_xor(mx,s));
  if(l==0){
    float e = wh1[(size_t)h*M+i]+mx;
    e = e>0.f? e:0.2f*e;
    mrow[(size_t)h*M+i] = (mx<-1e38f)?0.f:e;
  }
}

// ---- fused attention: P = exp(LR(wh1_i+wh2_j)-m_i) (masked), out = (P@V)/rowsum(P), ELU ----
// grid (N/32, H); block 256 = 4 waves; per-iter: compute P[32][64] tile -> MFMA with V from global
template<int FINAL>
__global__ void k_attn(const unsigned long long* __restrict__ adjw,
                       const float* __restrict__ wh1, const float* __restrict__ wh2,
                       const float* __restrict__ mrow,
                       const unsigned short* __restrict__ whT,
                       unsigned short* __restrict__ Hmat, float* __restrict__ outF){
  __shared__ unsigned short P[32][72];
  __shared__ float dsum[32];
  __shared__ float otile[32][68];
  const int M = Nn;
  int t=threadIdx.x;
  int h=blockIdx.y;
  int i0=blockIdx.x*32;
  int prow=t>>3, pc8=t&7;
  int i=i0+prow;
  float w1 = wh1[(size_t)h*M+i];
  float mi_ = mrow[(size_t)h*M+i];
  const unsigned long long* arow = adjw + (size_t)i*64;
  const float* w2h = wh2 + (size_t)h*M;
  int l=t&63, w=t>>6;
  int r0=(w&1)*16, c0=(w>>1)*32;
  int frow=l&15, fk=(l>>4)*8;
  const unsigned short* Vb = whT + (size_t)h*64*M;
  f32x4 acc[2]={};
  float lsum=0.f;
  for(int j0=0;j0<M;j0+=64){
    unsigned long long word = arow[j0>>6];
    unsigned bits = (unsigned)(word >> (pc8*8)) & 0xffu;
    float4 va = *(const float4*)(w2h + j0 + pc8*8);
    float4 vb = *(const float4*)(w2h + j0 + pc8*8 + 4);
    float pv[8]={va.x,va.y,va.z,va.w,vb.x,vb.y,vb.z,vb.w};
    union{ unsigned short s[8]; u32x4 v;} pu;
    #pragma unroll
    for(int q=0;q<8;q++){
      float e = w1 + pv[q];
      e = e>0.f ? e : 0.2f*e;
      float pe = (bits>>q & 1u) ? __expf(e - mi_) : 0.f;
      lsum += pe;
      pu.s[q] = f2bf(pe);
    }
    *(u32x4*)(&P[prow][pc8*8]) = pu.v;
    __syncthreads();
    #pragma unroll
    for(int ks=0;ks<2;ks++){
      short8 af = *(const short8*)(&P[r0+frow][ks*32+fk]);
      #pragma unroll
      for(int ct=0;ct<2;ct++){
        short8 bf = *(const short8*)(Vb + (size_t)(c0+ct*16+frow)*M + j0 + ks*32 + fk);
        acc[ct] = __builtin_amdgcn_mfma_f32_16x16x32_bf16(af, bf, acc[ct], 0,0,0);
      }
    }
    __syncthreads();
  }
  lsum += __shfl_xor(lsum,1);
  lsum += __shfl_xor(lsum,2);
  lsum += __shfl_xor(lsum,4);
  if(pc8==0) dsum[prow]=lsum;
  __syncthreads();
  #pragma unroll
  for(int ct=0;ct<2;ct++)
  #pragma unroll
  for(int r=0;r<4;r++){
    int orow = r0+(l>>4)*4+r;
    int ocol = c0+ct*16+(l&15);
    float d = fmaxf(dsum[orow], 1e-30f);
    float v = acc[ct][r]/d;
    v = v>0.f ? v : __expf(v)-1.f;   // ELU
    if(FINAL){
      otile[orow][ocol]=v;
    } else {
      Hmat[(size_t)(i0+orow)*O1 + h*64 + ocol] = f2bf(v);
    }
  }
  if(FINAL){
    __syncthreads();
    float vv[8]; float mx=-3e38f;
    #pragma unroll
    for(int q=0;q<8;q++){ vv[q]=otile[prow][pc8*8+q]; mx=fmaxf(mx,vv[q]); }
    mx=fmaxf(mx,__shfl_xor(mx,1));
    mx=fmaxf(mx,__shfl_xor(mx,2));
    mx=fmaxf(mx,__shfl_xor(mx,4));
    float s=0.f;
    #pragma unroll
    for(int q=0;q<8;q++) s += __expf(vv[q]-mx);
    s += __shfl_xor(s,1);
    s += __shfl_xor(s,2);
    s += __shfl_xor(s,4);
    float lg = mx + __logf(s);
    #pragma unroll
    for(int q=0;q<8;q++) outF[(size_t)i*64 + pc8*8 + q] = vv[q]-lg;
  }
}

extern "C" void kernel_launch(void* const* d_in, const int* in_sizes, int n_in,
                              void* d_out, int out_size, void* d_ws, size_t ws_size,
                              hipStream_t stream){
  const float* x  = (const float*)d_in[0];
  const int* adj  = (const int*)d_in[1];
  const float* W  = (const float*)d_in[2];
  const float* a1 = (const float*)d_in[3];
  const float* a2 = (const float*)d_in[4];
  const float* W2 = (const float*)d_in[5];
  const float* a21= (const float*)d_in[6];
  const float* a22= (const float*)d_in[7];
  float* out = (float*)d_out;
  char* ws = (char*)d_ws;

  // workspace layout (bytes)
  size_t off=0;
  unsigned long long* adjw = (unsigned long long*)(ws+off); off += (size_t)Nn*64*8;          // 2 MB
  unsigned short* xb   = (unsigned short*)(ws+off); off += (size_t)Nn*FIN*2;                 // 4 MB
  unsigned short* Wb   = (unsigned short*)(ws+off); off += (size_t)O1*FIN*2;                 // 0.5 MB
  unsigned short* W2b  = (unsigned short*)(ws+off); off += (size_t)64*FIN*2;                 // 64 KB
  unsigned short* whT1 = (unsigned short*)(ws+off); off += (size_t)O1*Nn*2;                  // 4 MB
  unsigned short* Hmat = (unsigned short*)(ws+off); off += (size_t)Nn*O1*2;                  // 4 MB
  unsigned short* whT2 = (unsigned short*)(ws+off); off += (size_t)64*Nn*2;                  // 0.5 MB
  float* wh1a = (float*)(ws+off); off += (size_t)NH*Nn*4;
  float* wh2a = (float*)(ws+off); off += (size_t)NH*Nn*4;
  float* mr1  = (float*)(ws+off); off += (size_t)NH*Nn*4;
  float* wh1b = (float*)(ws+off); off += (size_t)Nn*4;
  float* wh2b = (float*)(ws+off); off += (size_t)Nn*4;
  float* mrb  = (float*)(ws+off); off += (size_t)Nn*4;

  // 1) pack adjacency: 16.8M threads
  k_pack_adj<<<(Nn*(size_t)Nn)/256, 256, 0, stream>>>(adj, adjw);
  // 2) bf16 conversions
  k_cvt<<<(Nn*FIN/4+255)/256, 256, 0, stream>>>(x, xb, Nn*FIN);
  k_cvt<<<(O1*FIN/4+255)/256, 256, 0, stream>>>(W, Wb, O1*FIN);
  k_cvt<<<(64*FIN/4+255)/256, 256, 0, stream>>>(W2, W2b, 64*FIN);
  // 3) layer-1 projection: whT1[h*64+c][n]
  k_gemm_tn<<<dim3(Nn/64, O1/64), 256, 0, stream>>>(xb, Wb, whT1, Nn, FIN, O1);
  // 4) attention scalars
  k_wh12<<<dim3(Nn/256, NH), 256, 0, stream>>>(whT1, a1, a2, wh1a, wh2a);
  k_rowmax<<<dim3(Nn/4, NH), 256, 0, stream>>>(adjw, wh1a, wh2a, mr1);
  // 5) layer-1 fused attention -> Hmat (ELU'd, bf16)
  k_attn<0><<<dim3(Nn/32, NH), 256, 0, stream>>>(adjw, wh1a, wh2a, mr1, whT1, Hmat, nullptr);
  // 6) layer-2 projection: whT2[c][n]
  k_gemm_tn<<<dim3(Nn/64, 1), 256, 0, stream>>>(Hmat, W2b, whT2, Nn, FIN, 64);
  // 7) layer-2 attention scalars
  k_wh12<<<dim3(Nn/256, 1), 256, 0, stream>>>(whT2, a21, a22, wh1b, wh2b);
  k_rowmax<<<dim3(Nn/4, 1), 256, 0, stream>>>(adjw, wh1b, wh2b, mrb);
  // 8) layer-2 fused attention + ELU + log_softmax -> out
  k_attn<1><<<dim3(Nn/32, 1), 256, 0, stream>>>(adjw, wh1b, wh2b, mrb, whT2, nullptr, out);
  (void)in_sizes; (void)n_in; (void)out_size; (void)ws_size;
}

// Round 2
// 281.528 us; speedup vs baseline: 1.5696x; 1.5696x over previous
//
#include <hip/hip_runtime.h>

#define Nn 4096
#define FIN 512
#define NH 8
#define O1 512

typedef __attribute__((ext_vector_type(8))) short short8;
typedef __attribute__((ext_vector_type(4))) float f32x4;

__device__ __forceinline__ unsigned short f2bf(float f){
  union{float f; unsigned u;} x; x.f=f;
  unsigned r = x.u + 0x7fffu + ((x.u>>16)&1u);
  return (unsigned short)(r>>16);
}
__device__ __forceinline__ float bf2f(unsigned short b){
  union{unsigned u; float f;} x; x.u=((unsigned)b)<<16;
  return x.f;
}

// ---- pack adjacency int32 -> bitmask (one uint64 per 64 cols) ----
__global__ void k_pack_adj(const int* __restrict__ adj, unsigned long long* __restrict__ adjw){
  size_t tid = (size_t)blockIdx.x*blockDim.x + threadIdx.x;
  int v = adj[tid];
  unsigned long long m = __ballot(v>0);
  if((threadIdx.x&63)==0) adjw[tid>>6] = m;
}

// ---- f32 -> bf16 convert ----
__global__ void k_cvt(const float* __restrict__ in, unsigned short* __restrict__ out, int n){
  int i = (blockIdx.x*blockDim.x + threadIdx.x)*4;
  if(i>=n) return;
  float4 v = *(const float4*)(in+i);
  out[i+0]=f2bf(v.x); out[i+1]=f2bf(v.y); out[i+2]=f2bf(v.z); out[i+3]=f2bf(v.w);
}

// ---- C^T[o][m] = sum_k A[m][k]*B[o][k], bf16 in, bf16 out (transposed) ----
__global__ void k_gemm_tn(const unsigned short* __restrict__ A, const unsigned short* __restrict__ B,
                          unsigned short* __restrict__ CT, int M, int K, int O){
  int t=threadIdx.x, l=t&63, w=t>>6;
  int wm=w&1, wo=w>>1;
  int m0=blockIdx.x*64, o0=blockIdx.y*64;
  int row=l&15, kq=(l>>4)*8;
  const unsigned short* Ab = A + (size_t)(m0+wm*32+row)*K + kq;
  const unsigned short* Bb = B + (size_t)(o0+wo*32+row)*K + kq;
  f32x4 acc[2][2]={};
  for(int k0=0;k0<K;k0+=32){
    short8 a0=*(const short8*)(Ab+k0);
    short8 a1=*(const short8*)(Ab+(size_t)16*K+k0);
    short8 b0=*(const short8*)(Bb+k0);
    short8 b1=*(const short8*)(Bb+(size_t)16*K+k0);
    acc[0][0]=__builtin_amdgcn_mfma_f32_16x16x32_bf16(a0,b0,acc[0][0],0,0,0);
    acc[0][1]=__builtin_amdgcn_mfma_f32_16x16x32_bf16(a0,b1,acc[0][1],0,0,0);
    acc[1][0]=__builtin_amdgcn_mfma_f32_16x16x32_bf16(a1,b0,acc[1][0],0,0,0);
    acc[1][1]=__builtin_amdgcn_mfma_f32_16x16x32_bf16(a1,b1,acc[1][1],0,0,0);
  }
  #pragma unroll
  for(int mi=0;mi<2;mi++)
  #pragma unroll
  for(int oi=0;oi<2;oi++)
  #pragma unroll
  for(int r=0;r<4;r++){
    int m = m0+wm*32+mi*16+(l>>4)*4+r;
    int o = o0+wo*32+oi*16+(l&15);
    CT[(size_t)o*M+m] = f2bf(acc[mi][oi][r]);
  }
}

// ---- wh1[h][n] = sum_c whT[h*64+c][n]*a1[h][c]; same for wh2 ----
__global__ void k_wh12(const unsigned short* __restrict__ whT,
                       const float* __restrict__ a1, const float* __restrict__ a2,
                       float* __restrict__ wh1, float* __restrict__ wh2){
  const int M=Nn;
  int n=blockIdx.x*blockDim.x+threadIdx.x;
  int h=blockIdx.y;
  float s1=0.f,s2=0.f;
  for(int c=0;c<64;c++){
    float v=bf2f(whT[(size_t)(h*64+c)*M+n]);
    s1+=v*a1[h*64+c];
    s2+=v*a2[h*64+c];
  }
  wh1[(size_t)h*M+n]=s1;
  wh2[(size_t)h*M+n]=s2;
}

// ---- per-row softmax max: m_i = LR(wh1_i + max_{j in N(i)} wh2_j) ----
__global__ void k_rowmax(const unsigned long long* __restrict__ adjw,
                         const float* __restrict__ wh1, const float* __restrict__ wh2,
                         float* __restrict__ mrow){
  const int M=Nn;
  int w=threadIdx.x>>6, l=threadIdx.x&63;
  int i=blockIdx.x*4+w, h=blockIdx.y;
  unsigned long long word = adjw[(size_t)i*64 + l];
  const float* w2 = wh2 + (size_t)h*M + l*64;
  float mx=-3e38f;
  #pragma unroll
  for(int k=0;k<16;k++){
    float4 v=*(const float4*)(w2+k*4);
    unsigned b=(unsigned)(word>>(k*4))&0xfu;
    if(b&1u) mx=fmaxf(mx,v.x);
    if(b&2u) mx=fmaxf(mx,v.y);
    if(b&4u) mx=fmaxf(mx,v.z);
    if(b&8u) mx=fmaxf(mx,v.w);
  }
  #pragma unroll
  for(int s=32;s;s>>=1) mx=fmaxf(mx,__shfl_xor(mx,s));
  if(l==0){
    float e = wh1[(size_t)h*M+i]+mx;
    e = e>0.f? e:0.2f*e;
    mrow[(size_t)h*M+i] = (mx<-1e38f)?0.f:e;
  }
}

// ---- barrier-free fused attention ----
// Each wave owns RF*16 query rows and a j-chunk of Nn/NJS. P fragments are
// computed directly in MFMA A-layout registers (lane l: rows l&15 (+16*rf),
// k = 8*(l>>4)+q). Row softmax denominators via MFMA against a ones fragment
// (lands in C/D layout, no shuffles). One LDS tree at the end combines the
// NJS j-split partials. No __syncthreads in the main loop, no LDS P tile.
template<int FINAL, int NRT, int NJS, int RF, int LOGH>
__global__ __launch_bounds__(NRT*NJS*64, 4)
void k_attn2(const unsigned long long* __restrict__ adjw,
             const float* __restrict__ wh1, const float* __restrict__ wh2,
             const float* __restrict__ mrow,
             const unsigned short* __restrict__ whT,
             unsigned short* __restrict__ Hmat, float* __restrict__ outF){
  const int M = Nn;
  int t = threadIdx.x, l = t & 63, w = t >> 6;
  int lr = l & 15, g = l >> 4;
  int rt = w % NRT, js = w / NRT;
  int bid = blockIdx.x;
  int h = bid & ((1<<LOGH)-1);        // head in low bits -> pinned to one XCD
  int bx = bid >> LOGH;
  int i_base = bx * (NRT*RF*16) + rt * (RF*16);
  const float* w2h = wh2 + (size_t)h * M;
  const unsigned short* Vb = whT + (size_t)h * 64 * M;

  float w1f[RF], mi_[RF];
  const unsigned long long* arow[RF];
  #pragma unroll
  for (int rf = 0; rf < RF; rf++) {
    int i = i_base + rf*16 + lr;
    w1f[rf] = wh1[(size_t)h*M + i];
    mi_[rf] = mrow[(size_t)h*M + i];
    arow[rf] = adjw + (size_t)i * 64;
  }
  short8 ones;
  #pragma unroll
  for (int q=0;q<8;q++) ones[q] = (short)0x3F80;   // bf16 1.0

  f32x4 acc[RF][4] = {};
  f32x4 accd[RF] = {};
  const int chunk = Nn / NJS;
  const int jlo = js * chunk;

  for (int j0 = jlo; j0 < jlo + chunk; j0 += 64) {
    unsigned long long wrd[RF];
    #pragma unroll
    for (int rf=0; rf<RF; rf++) wrd[rf] = arow[rf][j0 >> 6];
    #pragma unroll
    for (int half = 0; half < 2; half++) {
      int j = j0 + half*32 + g*8;
      float4 va  = *(const float4*)(w2h + j);
      float4 vb4 = *(const float4*)(w2h + j + 4);
      float pv[8] = {va.x, va.y, va.z, va.w, vb4.x, vb4.y, vb4.z, vb4.w};
      short8 bfr[4];
      #pragma unroll
      for (int ct = 0; ct < 4; ct++)
        bfr[ct] = *(const short8*)(Vb + (size_t)(ct*16 + lr) * M + j);
      #pragma unroll
      for (int rf = 0; rf < RF; rf++) {
        unsigned bits = (unsigned)(wrd[rf] >> (half*32 + g*8)) & 0xffu;
        union { unsigned short s[8]; short8 v; } pu;
        #pragma unroll
        for (int q = 0; q < 8; q++) {
          float e = w1f[rf] + pv[q];
          e = fmaxf(e, 0.2f*e);            // LeakyReLU (monotone form)
          float p = __expf(e - mi_[rf]);
          p = (bits >> q & 1u) ? p : 0.f;
          pu.s[q] = f2bf(p);
        }
        #pragma unroll
        for (int ct = 0; ct < 4; ct++)
          acc[rf][ct] = __builtin_amdgcn_mfma_f32_16x16x32_bf16(pu.v, bfr[ct], acc[rf][ct], 0,0,0);
        accd[rf] = __builtin_amdgcn_mfma_f32_16x16x32_bf16(pu.v, ones, accd[rf], 0,0,0);
      }
    }
  }

  // ---- cross-wave j-split combine (log2(NJS) rounds) ----
  constexpr int NS = (NJS > 1) ? NJS/2 : 1;
  __shared__ float redA[NRT][NS][RF*16][65];
  __shared__ float redD[NRT][NS][RF*16];
  for (int s = NJS/2; s >= 1; s >>= 1) {
    if (js >= s && js < 2*s) {
      #pragma unroll
      for (int rf=0; rf<RF; rf++) {
        #pragma unroll
        for (int ct=0; ct<4; ct++)
          #pragma unroll
          for (int r=0; r<4; r++)
            redA[rt][js-s][rf*16+g*4+r][ct*16+lr] = acc[rf][ct][r];
        if (lr == 0) {
          #pragma unroll
          for (int r=0; r<4; r++)
            redD[rt][js-s][rf*16+g*4+r] = accd[rf][r];
        }
      }
    }
    __syncthreads();
    if (js < s) {
      #pragma unroll
      for (int rf=0; rf<RF; rf++) {
        #pragma unroll
        for (int ct=0; ct<4; ct++)
          #pragma unroll
          for (int r=0; r<4; r++)
            acc[rf][ct][r] += redA[rt][js][rf*16+g*4+r][ct*16+lr];
        #pragma unroll
        for (int r=0; r<4; r++)
          accd[rf][r] += redD[rt][js][rf*16+g*4+r];
      }
    }
    __syncthreads();
  }

  // ---- epilogue: normalize, ELU, (log_softmax) ----
  if (js == 0) {
    #pragma unroll
    for (int rf=0; rf<RF; rf++) {
      float vv[4][4];
      #pragma unroll
      for (int r=0; r<4; r++) {
        float d  = fmaxf(accd[rf][r], 1e-30f);
        float rd = 1.f/d;
        #pragma unroll
        for (int ct=0; ct<4; ct++) {
          float v = acc[rf][ct][r] * rd;
          vv[ct][r] = v > 0.f ? v : __expf(v) - 1.f;  // ELU
        }
      }
      if (FINAL) {
        #pragma unroll
        for (int r=0; r<4; r++) {
          float m = fmaxf(fmaxf(vv[0][r],vv[1][r]), fmaxf(vv[2][r],vv[3][r]));
          #pragma unroll
          for (int dd=1; dd<16; dd<<=1) m = fmaxf(m, __shfl_xor(m, dd));
          float sEx = 0.f;
          #pragma unroll
          for (int ct=0; ct<4; ct++) sEx += __expf(vv[ct][r] - m);
          #pragma unroll
          for (int dd=1; dd<16; dd<<=1) sEx += __shfl_xor(sEx, dd);
          float lg = m + __logf(sEx);
          int row = i_base + g*4 + r;
          #pragma unroll
          for (int ct=0; ct<4; ct++)
            outF[(size_t)row*64 + ct*16 + lr] = vv[ct][r] - lg;
        }
      } else {
        #pragma unroll
        for (int r=0; r<4; r++) {
          int row = i_base + rf*16 + g*4 + r;
          #pragma unroll
          for (int ct=0; ct<4; ct++)
            Hmat[(size_t)row*O1 + h*64 + ct*16 + lr] = f2bf(vv[ct][r]);
        }
      }
    }
  }
}

extern "C" void kernel_launch(void* const* d_in, const int* in_sizes, int n_in,
                              void* d_out, int out_size, void* d_ws, size_t ws_size,
                              hipStream_t stream){
  const float* x  = (const float*)d_in[0];
  const int* adj  = (const int*)d_in[1];
  const float* W  = (const float*)d_in[2];
  const float* a1 = (const float*)d_in[3];
  const float* a2 = (const float*)d_in[4];
  const float* W2 = (const float*)d_in[5];
  const float* a21= (const float*)d_in[6];
  const float* a22= (const float*)d_in[7];
  float* out = (float*)d_out;
  char* ws = (char*)d_ws;

  size_t off=0;
  unsigned long long* adjw = (unsigned long long*)(ws+off); off += (size_t)Nn*64*8;
  unsigned short* xb   = (unsigned short*)(ws+off); off += (size_t)Nn*FIN*2;
  unsigned short* Wb   = (unsigned short*)(ws+off); off += (size_t)O1*FIN*2;
  unsigned short* W2b  = (unsigned short*)(ws+off); off += (size_t)64*FIN*2;
  unsigned short* whT1 = (unsigned short*)(ws+off); off += (size_t)O1*Nn*2;
  unsigned short* Hmat = (unsigned short*)(ws+off); off += (size_t)Nn*O1*2;
  unsigned short* whT2 = (unsigned short*)(ws+off); off += (size_t)64*Nn*2;
  float* wh1a = (float*)(ws+off); off += (size_t)NH*Nn*4;
  float* wh2a = (float*)(ws+off); off += (size_t)NH*Nn*4;
  float* mr1  = (float*)(ws+off); off += (size_t)NH*Nn*4;
  float* wh1b = (float*)(ws+off); off += (size_t)Nn*4;
  float* wh2b = (float*)(ws+off); off += (size_t)Nn*4;
  float* mrb  = (float*)(ws+off); off += (size_t)Nn*4;

  k_pack_adj<<<(Nn*(size_t)Nn)/256, 256, 0, stream>>>(adj, adjw);
  k_cvt<<<(Nn*FIN/4+255)/256, 256, 0, stream>>>(x, xb, Nn*FIN);
  k_cvt<<<(O1*FIN/4+255)/256, 256, 0, stream>>>(W, Wb, O1*FIN);
  k_cvt<<<(64*FIN/4+255)/256, 256, 0, stream>>>(W2, W2b, 64*FIN);
  k_gemm_tn<<<dim3(Nn/64, O1/64), 256, 0, stream>>>(xb, Wb, whT1, Nn, FIN, O1);
  k_wh12<<<dim3(Nn/256, NH), 256, 0, stream>>>(whT1, a1, a2, wh1a, wh2a);
  k_rowmax<<<dim3(Nn/4, NH), 256, 0, stream>>>(adjw, wh1a, wh2a, mr1);
  // layer-1 attention: 2 row-tiles(32 rows) x 4 j-splits = 8 waves/block
  k_attn2<0, 2, 4, 2, 3><<<(Nn/64)*NH, 512, 0, stream>>>(adjw, wh1a, wh2a, mr1, whT1, Hmat, nullptr);
  k_gemm_tn<<<dim3(Nn/64, 1), 256, 0, stream>>>(Hmat, W2b, whT2, Nn, FIN, 64);
  k_wh12<<<dim3(Nn/256, 1), 256, 0, stream>>>(whT2, a21, a22, wh1b, wh2b);
  k_rowmax<<<dim3(Nn/4, 1), 256, 0, stream>>>(adjw, wh1b, wh2b, mrb);
  // layer-2 attention: 1 row-tile(16 rows) x 16 j-splits = 16 waves/block
  k_attn2<1, 1, 16, 1, 0><<<Nn/16, 1024, 0, stream>>>(adjw, wh1b, wh2b, mrb, whT2, nullptr, out);
  (void)in_sizes; (void)n_in; (void)out_size; (void)ws_size;
}

// Round 4
// 175.003 us; speedup vs baseline: 2.5250x; 1.6087x over previous
//
#include <hip/hip_runtime.h>

#define Nn 4096
#define FIN 512
#define NH 8
#define O1 512
#define LOG2E 1.44269504088896f

typedef __attribute__((ext_vector_type(8))) short short8;
typedef __attribute__((ext_vector_type(4))) float f32x4;

__device__ __forceinline__ unsigned short f2bf(float f){
  union{float f; unsigned u;} x; x.f=f;
  unsigned r = x.u + 0x7fffu + ((x.u>>16)&1u);
  return (unsigned short)(r>>16);
}
__device__ __forceinline__ float bf2f(unsigned short b){
  union{unsigned u; float f;} x; x.u=((unsigned)b)<<16;
  return x.f;
}
// packed f32x2 -> bf16x2 (RNE), single instruction; non-volatile so the
// scheduler can move it freely
__device__ __forceinline__ unsigned cvtpk_bf16(float a, float b){
  unsigned r; asm("v_cvt_pk_bf16_f32 %0, %1, %2" : "=v"(r) : "v"(a), "v"(b));
  return r;
}

// ---- pack adjacency int32 -> bitmask (one uint64 per 64 cols) ----
__global__ void k_pack_adj(const int* __restrict__ adj, unsigned long long* __restrict__ adjw){
  size_t tid = (size_t)blockIdx.x*blockDim.x + threadIdx.x;
  int v = adj[tid];
  unsigned long long m = __ballot(v>0);
  if((threadIdx.x&63)==0) adjw[tid>>6] = m;
}

// ---- f32 -> bf16 convert ----
__global__ void k_cvt(const float* __restrict__ in, unsigned short* __restrict__ out, int n){
  int i = (blockIdx.x*blockDim.x + threadIdx.x)*4;
  if(i>=n) return;
  float4 v = *(const float4*)(in+i);
  out[i+0]=f2bf(v.x); out[i+1]=f2bf(v.y); out[i+2]=f2bf(v.z); out[i+3]=f2bf(v.w);
}

// ---- K-split GEMM: C^T[o][m] = sum_k A[m][k]*B[o][k] ----
// block tile 32 rows x NWC*32 cols; waves = NWC x KS (K split KS ways),
// one LDS tree combine. Grid (M/32, O/(NWC*32)).
template<int NWC, int KS>
__global__ __launch_bounds__(NWC*KS*64, 2)
void k_gemm3(const unsigned short* __restrict__ A, const unsigned short* __restrict__ B,
             unsigned short* __restrict__ CT, int M, int K, int O){
  int t=threadIdx.x, l=t&63, w=t>>6;
  int wc=w%NWC, ks=w/NWC;
  int m0=blockIdx.x*32, o0=blockIdx.y*(NWC*32);
  int row=l&15, kq=(l>>4)*8, g=l>>4;
  int kw=K/KS;
  const unsigned short* Ab = A + (size_t)(m0+row)*K + ks*kw + kq;
  const unsigned short* Bb = B + (size_t)(o0+wc*32+row)*K + ks*kw + kq;
  f32x4 acc[2][2]={};
  #pragma unroll 2
  for(int k0=0;k0<kw;k0+=32){
    short8 a0=*(const short8*)(Ab+k0);
    short8 a1=*(const short8*)(Ab+(size_t)16*K+k0);
    short8 b0=*(const short8*)(Bb+k0);
    short8 b1=*(const short8*)(Bb+(size_t)16*K+k0);
    acc[0][0]=__builtin_amdgcn_mfma_f32_16x16x32_bf16(a0,b0,acc[0][0],0,0,0);
    acc[0][1]=__builtin_amdgcn_mfma_f32_16x16x32_bf16(a0,b1,acc[0][1],0,0,0);
    acc[1][0]=__builtin_amdgcn_mfma_f32_16x16x32_bf16(a1,b0,acc[1][0],0,0,0);
    acc[1][1]=__builtin_amdgcn_mfma_f32_16x16x32_bf16(a1,b1,acc[1][1],0,0,0);
  }
  __shared__ float red[NWC][KS/2][32][33];
  for(int s=KS/2;s>=1;s>>=1){
    if(ks>=s && ks<2*s){
      #pragma unroll
      for(int mi=0;mi<2;mi++)
      #pragma unroll
      for(int oi=0;oi<2;oi++)
      #pragma unroll
      for(int r=0;r<4;r++)
        red[wc][ks-s][mi*16+g*4+r][oi*16+row]=acc[mi][oi][r];
    }
    __syncthreads();
    if(ks<s){
      #pragma unroll
      for(int mi=0;mi<2;mi++)
      #pragma unroll
      for(int oi=0;oi<2;oi++)
      #pragma unroll
      for(int r=0;r<4;r++)
        acc[mi][oi][r]+=red[wc][ks][mi*16+g*4+r][oi*16+row];
    }
    __syncthreads();
  }
  if(ks==0){
    #pragma unroll
    for(int mi=0;mi<2;mi++)
    #pragma unroll
    for(int oi=0;oi<2;oi++)
    #pragma unroll
    for(int r=0;r<4;r++){
      int m=m0+mi*16+g*4+r;
      int o=o0+wc*32+oi*16+row;
      CT[(size_t)o*M+m]=f2bf(acc[mi][oi][r]);
    }
  }
}

// ---- wh1[h][n] = LOG2E * sum_c whT[h*64+c][n]*a1[h][c]; same for wh2 ----
// Prescaled by log2(e): LeakyReLU is positively homogeneous, so
// LR(w1+w2)*log2e = LR(w1s+w2s), and exp(x) = exp2(xs).
__global__ void k_wh12(const unsigned short* __restrict__ whT,
                       const float* __restrict__ a1, const float* __restrict__ a2,
                       float* __restrict__ wh1, float* __restrict__ wh2){
  const int M=Nn;
  int n=blockIdx.x*blockDim.x+threadIdx.x;
  int h=blockIdx.y;
  float s1=0.f,s2=0.f;
  for(int c=0;c<64;c++){
    float v=bf2f(whT[(size_t)(h*64+c)*M+n]);
    s1+=v*a1[h*64+c];
    s2+=v*a2[h*64+c];
  }
  wh1[(size_t)h*M+n]=s1*LOG2E;
  wh2[(size_t)h*M+n]=s2*LOG2E;
}

// ---- barrier-free fused attention (no max-shift: cancels in normalization) ----
// P fragments computed directly in MFMA A-layout registers; denominator via
// MFMA against ones; NJS j-split waves combined by one LDS tree at the end.
template<int FINAL, int NJS, int RF, int LOGH>
__global__ __launch_bounds__(NJS*64, 4)
void k_attn3(const unsigned long long* __restrict__ adjw,
             const float* __restrict__ wh1, const float* __restrict__ wh2,
             const unsigned short* __restrict__ whT,
             unsigned short* __restrict__ Hmat, float* __restrict__ outF){
  const int M = Nn;
  int t = threadIdx.x, l = t & 63, js = t >> 6;
  int lr = l & 15, g = l >> 4;
  int bid = blockIdx.x;
  int h = bid & ((1<<LOGH)-1);        // head in low bits -> pinned per XCD
  int bx = bid >> LOGH;
  int i_base = bx * (RF*16);
  const float* w2h = wh2 + (size_t)h * M;
  const unsigned short* Vb = whT + (size_t)h * 64 * M;

  float w1f[RF];
  const unsigned long long* arow[RF];
  #pragma unroll
  for (int rf = 0; rf < RF; rf++) {
    int i = i_base + rf*16 + lr;
    w1f[rf] = wh1[(size_t)h*M + i];
    arow[rf] = adjw + (size_t)i * 64;
  }
  short8 ones;
  #pragma unroll
  for (int q=0;q<8;q++) ones[q] = (short)0x3F80;   // bf16 1.0

  f32x4 acc[RF][4] = {};
  f32x4 accd[RF] = {};
  const int chunk = Nn / NJS;
  const int jlo = js * chunk;

  #pragma unroll 2
  for (int j0 = jlo; j0 < jlo + chunk; j0 += 64) {
    unsigned long long wrd[RF];
    #pragma unroll
    for (int rf=0; rf<RF; rf++) wrd[rf] = arow[rf][j0 >> 6];
    #pragma unroll
    for (int half = 0; half < 2; half++) {
      int j = j0 + half*32 + g*8;
      float4 va  = *(const float4*)(w2h + j);
      float4 vb4 = *(const float4*)(w2h + j + 4);
      float pv[8] = {va.x, va.y, va.z, va.w, vb4.x, vb4.y, vb4.z, vb4.w};
      short8 bfr[4];
      #pragma unroll
      for (int ct = 0; ct < 4; ct++)
        bfr[ct] = *(const short8*)(Vb + (size_t)(ct*16 + lr) * M + j);
      #pragma unroll
      for (int rf = 0; rf < RF; rf++) {
        unsigned bits = (unsigned)(wrd[rf] >> (half*32 + g*8)) & 0xffu;
        float pf[8];
        #pragma unroll
        for (int q = 0; q < 8; q++) {
          float e = w1f[rf] + pv[q];
          e = fmaxf(e, 0.2f*e);                 // LeakyReLU (scaled domain)
          float p = __builtin_amdgcn_exp2f(e);  // raw v_exp_f32
          int mk = (int)(bits << (31-q)) >> 31; // -1 if edge present else 0
          pf[q] = __uint_as_float(__float_as_uint(p) & (unsigned)mk);
        }
        union { unsigned u[4]; short8 v; } pu;
        #pragma unroll
        for (int k = 0; k < 4; k++) pu.u[k] = cvtpk_bf16(pf[2*k], pf[2*k+1]);
        #pragma unroll
        for (int ct = 0; ct < 4; ct++)
          acc[rf][ct] = __builtin_amdgcn_mfma_f32_16x16x32_bf16(pu.v, bfr[ct], acc[rf][ct], 0,0,0);
        accd[rf] = __builtin_amdgcn_mfma_f32_16x16x32_bf16(pu.v, ones, accd[rf], 0,0,0);
      }
    }
  }

  // ---- cross-wave j-split combine ----
  constexpr int NS = NJS/2;
  __shared__ float redA[NS][RF*16][65];
  __shared__ float redD[NS][RF*16];
  for (int s = NJS/2; s >= 1; s >>= 1) {
    if (js >= s && js < 2*s) {
      #pragma unroll
      for (int rf=0; rf<RF; rf++) {
        #pragma unroll
        for (int ct=0; ct<4; ct++)
          #pragma unroll
          for (int r=0; r<4; r++)
            redA[js-s][rf*16+g*4+r][ct*16+lr] = acc[rf][ct][r];
        if (lr == 0) {
          #pragma unroll
          for (int r=0; r<4; r++)
            redD[js-s][rf*16+g*4+r] = accd[rf][r];
        }
      }
    }
    __syncthreads();
    if (js < s) {
      #pragma unroll
      for (int rf=0; rf<RF; rf++) {
        #pragma unroll
        for (int ct=0; ct<4; ct++)
          #pragma unroll
          for (int r=0; r<4; r++)
            acc[rf][ct][r] += redA[js][rf*16+g*4+r][ct*16+lr];
        #pragma unroll
        for (int r=0; r<4; r++)
          accd[rf][r] += redD[js][rf*16+g*4+r];
      }
    }
    __syncthreads();
  }

  // ---- epilogue: normalize, ELU, (log_softmax) ----
  if (js == 0) {
    #pragma unroll
    for (int rf=0; rf<RF; rf++) {
      float vv[4][4];
      #pragma unroll
      for (int r=0; r<4; r++) {
        float d  = fmaxf(accd[rf][r], 1e-30f);
        float rd = 1.f/d;
        #pragma unroll
        for (int ct=0; ct<4; ct++) {
          float v = acc[rf][ct][r] * rd;
          vv[ct][r] = v > 0.f ? v : __expf(v) - 1.f;  // ELU
        }
      }
      if (FINAL) {
        #pragma unroll
        for (int r=0; r<4; r++) {
          float m = fmaxf(fmaxf(vv[0][r],vv[1][r]), fmaxf(vv[2][r],vv[3][r]));
          #pragma unroll
          for (int dd=1; dd<16; dd<<=1) m = fmaxf(m, __shfl_xor(m, dd));
          float sEx = 0.f;
          #pragma unroll
          for (int ct=0; ct<4; ct++) sEx += __expf(vv[ct][r] - m);
          #pragma unroll
          for (int dd=1; dd<16; dd<<=1) sEx += __shfl_xor(sEx, dd);
          float lg = m + __logf(sEx);
          int row = i_base + g*4 + r;
          #pragma unroll
          for (int ct=0; ct<4; ct++)
            outF[(size_t)row*64 + ct*16 + lr] = vv[ct][r] - lg;
        }
      } else {
        #pragma unroll
        for (int r=0; r<4; r++) {
          int row = i_base + rf*16 + g*4 + r;
          #pragma unroll
          for (int ct=0; ct<4; ct++)
            Hmat[(size_t)row*O1 + h*64 + ct*16 + lr] = f2bf(vv[ct][r]);
        }
      }
    }
  }
}

extern "C" void kernel_launch(void* const* d_in, const int* in_sizes, int n_in,
                              void* d_out, int out_size, void* d_ws, size_t ws_size,
                              hipStream_t stream){
  const float* x  = (const float*)d_in[0];
  const int* adj  = (const int*)d_in[1];
  const float* W  = (const float*)d_in[2];
  const float* a1 = (const float*)d_in[3];
  const float* a2 = (const float*)d_in[4];
  const float* W2 = (const float*)d_in[5];
  const float* a21= (const float*)d_in[6];
  const float* a22= (const float*)d_in[7];
  float* out = (float*)d_out;
  char* ws = (char*)d_ws;

  size_t off=0;
  unsigned long long* adjw = (unsigned long long*)(ws+off); off += (size_t)Nn*64*8;
  unsigned short* xb   = (unsigned short*)(ws+off); off += (size_t)Nn*FIN*2;
  unsigned short* Wb   = (unsigned short*)(ws+off); off += (size_t)O1*FIN*2;
  unsigned short* W2b  = (unsigned short*)(ws+off); off += (size_t)64*FIN*2;
  unsigned short* whT1 = (unsigned short*)(ws+off); off += (size_t)O1*Nn*2;
  unsigned short* Hmat = (unsigned short*)(ws+off); off += (size_t)Nn*O1*2;
  unsigned short* whT2 = (unsigned short*)(ws+off); off += (size_t)64*Nn*2;
  float* wh1a = (float*)(ws+off); off += (size_t)NH*Nn*4;
  float* wh2a = (float*)(ws+off); off += (size_t)NH*Nn*4;
  float* wh1b = (float*)(ws+off); off += (size_t)Nn*4;
  float* wh2b = (float*)(ws+off); off += (size_t)Nn*4;

  k_pack_adj<<<(Nn*(size_t)Nn)/256, 256, 0, stream>>>(adj, adjw);
  k_cvt<<<(Nn*FIN/4+255)/256, 256, 0, stream>>>(x, xb, Nn*FIN);
  k_cvt<<<(O1*FIN/4+255)/256, 256, 0, stream>>>(W, Wb, O1*FIN);
  k_cvt<<<(64*FIN/4+255)/256, 256, 0, stream>>>(W2, W2b, 64*FIN);
  // layer-1 projection: 32x64 tiles, 4-way K-split -> 8192 waves
  k_gemm3<2,4><<<dim3(Nn/32, O1/64), 512, 0, stream>>>(xb, Wb, whT1, Nn, FIN, O1);
  k_wh12<<<dim3(Nn/256, NH), 256, 0, stream>>>(whT1, a1, a2, wh1a, wh2a);
  // layer-1 attention: 32 rows/block, 8 j-split waves, grid 1024
  k_attn3<0, 8, 2, 3><<<(Nn/32)*NH, 512, 0, stream>>>(adjw, wh1a, wh2a, whT1, Hmat, nullptr);
  // layer-2 projection: 8-way K-split -> 2048 waves
  k_gemm3<2,8><<<dim3(Nn/32, 1), 1024, 0, stream>>>(Hmat, W2b, whT2, Nn, FIN, 64);
  k_wh12<<<dim3(Nn/256, 1), 256, 0, stream>>>(whT2, a21, a22, wh1b, wh2b);
  // layer-2 attention: 16 rows/block, 16 j-split waves, grid 256
  k_attn3<1, 16, 1, 0><<<Nn/16, 1024, 0, stream>>>(adjw, wh1b, wh2b, whT2, nullptr, out);
  (void)in_sizes; (void)n_in; (void)out_size; (void)ws_size;
}